// Round 7
// baseline (145.441 us; speedup 1.0000x reference)
//
#include <hip/hip_runtime.h>
#include <stdint.h>

#define N_PTS 131072
#define NCLS 8
#define MT 64      // points per tile
#define CAP 32768  // per-class capacity (~16.4k actual)
#define PS 2.8853900817779268f  // 2*log2(e) weight prescale

typedef __bf16 bf16x8 __attribute__((ext_vector_type(8)));
typedef float f32x4 __attribute__((ext_vector_type(4)));

__device__ __forceinline__ float exp2_fast(float a) {
#if __has_builtin(__builtin_amdgcn_exp2f)
  return __builtin_amdgcn_exp2f(a);
#else
  return exp2f(a);
#endif
}

// tanh(x) with a = PS*x: tanh = 1 - 2/(2^a + 1)
__device__ __forceinline__ float tanh_p2(float a) {
  return fmaf(-2.0f, __builtin_amdgcn_rcpf(exp2_fast(a) + 1.0f), 1.0f);
}

__device__ __forceinline__ unsigned short f2bf_rne(float f) {
  unsigned u = __float_as_uint(f);
  u = u + 0x7fffu + ((u >> 16) & 1u);
  return (unsigned short)(u >> 16);
}

// pack two floats to bf16 pair (round-half-up): {lo16: bf(a), hi16: bf(b)}
__device__ __forceinline__ unsigned pack_bf16(float a, float b) {
  unsigned ua = __float_as_uint(a) + 0x8000u;
  unsigned ub = __float_as_uint(b) + 0x8000u;
  return __builtin_amdgcn_perm(ub, ua, 0x07060302u);
}

// ---------------- fused prep kernel ----------------
// hdr ints [0..7] = per-class cursors (memset to 0 before launch).
// packed23: bf16 [l(2)][c][k/8][j][k%8] — A-frags, value = PS*W[k][j]
#define PK2_BLKS 512
#define MISC_BLKS 177
#define MISC_N 45184
#define SCAT_BLKS 512
#define PREP_GRID (PK2_BLKS + MISC_BLKS + SCAT_BLKS)

__global__ __launch_bounds__(256) void k_prep(
    const int* __restrict__ times,
    const float* __restrict__ W1, const float* __restrict__ b1,
    const float* __restrict__ W2, const float* __restrict__ b2,
    const float* __restrict__ W3, const float* __restrict__ b3,
    const float* __restrict__ W4, const float* __restrict__ b4,
    int* __restrict__ hdr, int* __restrict__ sortedIdx,
    unsigned short* __restrict__ packed23,
    float* __restrict__ w1p, float* __restrict__ b2p,
    float* __restrict__ b3p, float* __restrict__ b4p,
    unsigned short* __restrict__ W4p) {
  __shared__ int lh[NCLS], lbase[NCLS];

  int b = blockIdx.x;
  int tid = threadIdx.x;

  if (b < PK2_BLKS) {
    int cl = b >> 5;               // 0..15
    int k8 = b & 31;
    int j = tid;
    int l = cl >> 3, c = cl & 7;
    const float* W = (l ? W3 : W2) + c * 65536 + k8 * 8 * 256 + j;
    float v0 = W[0],        v1 = W[256],     v2 = W[2 * 256], v3 = W[3 * 256];
    float v4 = W[4 * 256],  v5 = W[5 * 256], v6 = W[6 * 256], v7 = W[7 * 256];
    uint4 pk;
    pk.x = (unsigned)f2bf_rne(PS * v0) | ((unsigned)f2bf_rne(PS * v1) << 16);
    pk.y = (unsigned)f2bf_rne(PS * v2) | ((unsigned)f2bf_rne(PS * v3) << 16);
    pk.z = (unsigned)f2bf_rne(PS * v4) | ((unsigned)f2bf_rne(PS * v5) << 16);
    pk.w = (unsigned)f2bf_rne(PS * v6) | ((unsigned)f2bf_rne(PS * v7) << 16);
    *(uint4*)&packed23[cl * 65536 + (k8 * 256 + j) * 8] = pk;
  } else if (b < PK2_BLKS + MISC_BLKS) {
    int e2 = (b - PK2_BLKS) * 256 + tid;
    if (e2 < 8192) {          // w1p: [c][j][4] = PS*{w0,w1,w2,b}
      int c = e2 >> 10, rem = e2 & 1023;
      int j = rem >> 2, t = rem & 3;
      float v = (t < 3) ? W1[c * 768 + t * 256 + j] : b1[c * 256 + j];
      w1p[e2] = PS * v;
    } else if (e2 < 10240) {
      int i = e2 - 8192;
      b2p[i] = PS * b2[i];
    } else if (e2 < 12288) {
      int i = e2 - 10240;
      b3p[i] = PS * b3[i];
    } else if (e2 < 12416) {  // b4p: [c][16]
      int i = e2 - 12288;
      int c = i >> 4, r = i & 15;
      b4p[i] = (r < 3) ? PS * b4[c * 3 + r] : 0.0f;
    } else if (e2 < MISC_N) { // W4p: [c][k/8][j(16)][k%8]
      int i = e2 - 12416;
      int c = i >> 12, rem = i & 4095;
      int jj = rem & 7, j = (rem >> 3) & 15, k = ((rem >> 7) << 3) + jj;
      float v = (j < 3) ? PS * W4[c * 768 + k * 3 + j] : 0.0f;
      W4p[c * 4096 + rem] = f2bf_rne(v);
    }
  } else {
    int sb = b - (PK2_BLKS + MISC_BLKS);
    if (tid < NCLS) lh[tid] = 0;
    __syncthreads();
    int i = sb * 256 + tid;
    int t = times[i];
    int r = atomicAdd(&lh[t], 1);
    __syncthreads();
    if (tid < NCLS) lbase[tid] = lh[tid] ? atomicAdd(&hdr[tid], lh[tid]) : 0;
    __syncthreads();
    sortedIdx[t * CAP + lbase[t] + r] = i;
  }
}

// ---------------- main MLP kernel ----------------
// 256 thr = 4 waves; wave w owns j in [w*64, w*64+64).
// Phase-interleaved in-place pipeline: each layer splits into half-k-loops
// P(mh) (reads Abuf cols m in [mh*32, mh*32+32) only) and half-epilogues
// E(mh) (writes those same cols only). Segments between barriers pair an
// MFMA stream with an independent VALU stream so both pipes stay fed:
//   L1h0 |bar| L1h1+P0(L2) |bar| P1(L2)+E0(L2) |bar| E1(L2)+P0(L3) |bar|
//   P1(L3)+E0(L3) |bar| E1(L3) |bar| L4
__global__ __launch_bounds__(256, 4) void k_mlp(
    const float* __restrict__ pos,
    const int* __restrict__ hdr, const int* __restrict__ sortedIdx,
    const unsigned short* __restrict__ packed23,
    const float* __restrict__ w1p, const float* __restrict__ b2p,
    const float* __restrict__ b3p, const float* __restrict__ b4p,
    const unsigned short* __restrict__ W4p,
    float* __restrict__ out) {

  __shared__ __align__(16) unsigned short Abuf[32][MT][8];  // 32 KB
  __shared__ __align__(16) float4 w1i[256];                 // 4 KB
  __shared__ __align__(16) float xpos[MT][4];               // 1 KB
  __shared__ int sIdx[MT];

  int b = blockIdx.x;
  int tid = threadIdx.x;

  // derive (class, tile) from per-class counts
  int c = -1, t0 = 0, cnt = 0;
  {
    int ts = 0;
#pragma unroll
    for (int cc = 0; cc < NCLS; cc++) {
      int cc_cnt = hdr[cc];
      int tiles = (cc_cnt + MT - 1) >> 6;
      if (b >= ts && b < ts + tiles) { c = cc; t0 = b - ts; cnt = cc_cnt; }
      ts += tiles;
    }
  }
  if (c < 0) return;
  int base = c * CAP + t0 * MT;
  int mCount = min(MT, cnt - t0 * MT);

  int lane = tid & 63, w = tid >> 6;
  int quad = lane >> 4, l16 = lane & 15;
  int jbase = w * 64;

  // ---- stage: sIdx + xpos (direct gather) + w1 weights, one barrier ----
  if (tid < MT) sIdx[tid] = sortedIdx[base + min(tid, mCount - 1)];
  if (tid < MT * 3) {
    int m = tid / 3, comp = tid - 3 * m;
    int idx = sortedIdx[base + min(m, mCount - 1)];
    xpos[m][comp] = pos[idx * 3 + comp];
  }
  w1i[tid] = ((const float4*)(w1p + (size_t)c * 1024))[tid];

  const bf16x8* Af2 = (const bf16x8*)(packed23 + ((size_t)c << 16));
  const bf16x8* Af3 = (const bf16x8*)(packed23 + ((size_t)(8 + c) << 16));
  const float* bias2 = b2p + c * 256;
  const float* bias3 = b3p + c * 256;

  // layer-1 half: columns m in [mh*32, mh*32+32), thread covers 32 j
  auto l1half = [&](int mh) {
    int m = (tid & 31) + mh * 32;
    int jq = tid >> 5;  // 0..7
    float x0 = xpos[m][0], x1 = xpos[m][1], x2 = xpos[m][2];
#pragma unroll
    for (int i8 = 0; i8 < 4; i8++) {
      int j8 = jq * 4 + i8;
      unsigned pk[4];
#pragma unroll
      for (int jp = 0; jp < 4; jp++) {
        float t[2];
#pragma unroll
        for (int u = 0; u < 2; u++) {
          float4 wv = w1i[j8 * 8 + jp * 2 + u];
          float a = fmaf(x0, wv.x, fmaf(x1, wv.y, fmaf(x2, wv.z, wv.w)));
          t[u] = tanh_p2(a);
        }
        pk[jp] = pack_bf16(t[0], t[1]);
      }
      *(uint4*)&Abuf[j8][m][0] = make_uint4(pk[0], pk[1], pk[2], pk[3]);
    }
  };

  // half-k-loop: acc for cols m in [mh*32, +32); reads only those cols
  auto pfun = [&](const bf16x8* __restrict__ Af, const float* __restrict__ biasp,
                  int mh, f32x4 (&acc)[4][2]) {
#pragma unroll
    for (int jf = 0; jf < 4; jf++) {
      f32x4 bv = *(const f32x4*)&biasp[jbase + jf * 16 + quad * 4];
      acc[jf][0] = bv;
      acc[jf][1] = bv;
    }
#pragma unroll
    for (int kb = 0; kb < 8; kb++) {
      int kq = kb * 4 + quad;
      bf16x8 af[4], bfr[2];
#pragma unroll
      for (int jf = 0; jf < 4; jf++)
        af[jf] = Af[kq * 256 + jbase + jf * 16 + l16];
#pragma unroll
      for (int mt = 0; mt < 2; mt++)
        bfr[mt] = *(const bf16x8*)&Abuf[kq][(mh * 2 + mt) * 16 + l16][0];
#pragma unroll
      for (int jf = 0; jf < 4; jf++)
#pragma unroll
        for (int mt = 0; mt < 2; mt++)
          acc[jf][mt] = __builtin_amdgcn_mfma_f32_16x16x32_bf16(af[jf], bfr[mt], acc[jf][mt], 0, 0, 0);
    }
  };

  // half-epilogue: tanh+pack+write cols m in [mh*32, +32) only
  auto efun = [&](f32x4 (&acc)[4][2], int mh) {
#pragma unroll
    for (int jf = 0; jf < 4; jf++) {
      int jbq = jbase + jf * 16 + quad * 4;  // 4 consecutive j per lane
#pragma unroll
      for (int mt = 0; mt < 2; mt++) {
        int m = (mh * 2 + mt) * 16 + l16;
        float t0 = tanh_p2(acc[jf][mt][0]);
        float t1 = tanh_p2(acc[jf][mt][1]);
        float t2 = tanh_p2(acc[jf][mt][2]);
        float t3 = tanh_p2(acc[jf][mt][3]);
        uint2 pk = make_uint2(pack_bf16(t0, t1), pack_bf16(t2, t3));
        *(uint2*)&Abuf[jbq >> 3][m][jbq & 7] = pk;
      }
    }
  };

  f32x4 accA[4][2], accB[4][2];

  __syncthreads();
  l1half(0);
  __syncthreads();
  l1half(1);            // VALU stream (writes m23)
  pfun(Af2, bias2, 0, accA);  // MFMA stream (reads m01)
  __syncthreads();
  pfun(Af2, bias2, 1, accB);  // MFMA (reads m23)
  efun(accA, 0);              // VALU (writes m01)
  __syncthreads();
  efun(accB, 1);              // VALU (writes m23, layer-2 out)
  pfun(Af3, bias3, 0, accA);  // MFMA (reads m01, layer-2 out)
  __syncthreads();
  pfun(Af3, bias3, 1, accB);  // MFMA (reads m23)
  efun(accA, 0);              // VALU (writes m01, layer-3 out)
  __syncthreads();
  efun(accB, 1);              // VALU (writes m23)
  __syncthreads();

  // ---- layer 4 (16x16x32 MFMA, j padded 3->16): wave w -> m-tile w ----
  {
    f32x4 acc = *(const f32x4*)&b4p[c * 16 + quad * 4];
#pragma unroll
    for (int kb = 0; kb < 8; kb++) {
      int kq = kb * 4 + quad;
      bf16x8 a4 = *(const bf16x8*)&W4p[((size_t)c * 512 + kq * 16 + l16) * 8];
      bf16x8 b4f = *(const bf16x8*)&Abuf[kq][w * 16 + l16][0];
      acc = __builtin_amdgcn_mfma_f32_16x16x32_bf16(a4, b4f, acc, 0, 0, 0);
    }
    int m = w * 16 + l16;
    if (quad == 0 && m < mCount) {
      int o = sIdx[m] * 3;
      out[o + 0] = tanh_p2(acc[0]);
      out[o + 1] = tanh_p2(acc[1]);
      out[o + 2] = tanh_p2(acc[2]);
    }
  }
}

extern "C" void kernel_launch(void* const* d_in, const int* in_sizes, int n_in,
                              void* d_out, int out_size, void* d_ws, size_t ws_size,
                              hipStream_t stream) {
  const float* pos = (const float*)d_in[0];
  const int* times = (const int*)d_in[1];
  const float* W1 = (const float*)d_in[2];
  const float* b1 = (const float*)d_in[3];
  const float* W2 = (const float*)d_in[4];
  const float* b2 = (const float*)d_in[5];
  const float* W3 = (const float*)d_in[6];
  const float* b3 = (const float*)d_in[7];
  const float* W4 = (const float*)d_in[8];
  const float* b4 = (const float*)d_in[9];

  char* ws = (char*)d_ws;
  int* hdr = (int*)ws;
  int* sortedIdx = (int*)(ws + 4096);                    // 1 MB
  float* w1p = (float*)(ws + 1052672);                   // 32 KB
  float* b2p = (float*)(ws + 1085440);                   // 8 KB
  float* b3p = (float*)(ws + 1093632);                   // 8 KB
  float* b4p = (float*)(ws + 1101824);                   // 512 B
  unsigned short* W4p = (unsigned short*)(ws + 1102336); // 64 KB
  unsigned short* packed23 = (unsigned short*)(ws + (2u << 20)); // 2 MB
  float* out = (float*)d_out;

  hipMemsetAsync(d_ws, 0, 64, stream);
  k_prep<<<PREP_GRID, 256, 0, stream>>>(times, W1, b1, W2, b2, W3, b3, W4, b4,
                                        hdr, sortedIdx, packed23,
                                        w1p, b2p, b3p, b4p, W4p);
  k_mlp<<<N_PTS / MT + NCLS, 256, 0, stream>>>(
      pos, hdr, sortedIdx, packed23, w1p, b2p, b3p, b4p, W4p, out);
}

// Round 8
// 135.599 us; speedup vs baseline: 1.0726x; 1.0726x over previous
//
#include <hip/hip_runtime.h>
#include <stdint.h>

#define N_PTS 131072
#define NCLS 8
#define CAP 32768  // per-class capacity (~16.4k actual)
#define PS 2.8853900817779268f  // 2*log2(e) weight prescale

typedef __bf16 bf16x8 __attribute__((ext_vector_type(8)));
typedef float f32x4 __attribute__((ext_vector_type(4)));

__device__ __forceinline__ float exp2_fast(float a) {
#if __has_builtin(__builtin_amdgcn_exp2f)
  return __builtin_amdgcn_exp2f(a);
#else
  return exp2f(a);
#endif
}

// tanh(x) with a = PS*x: tanh = 1 - 2/(2^a + 1)
__device__ __forceinline__ float tanh_p2(float a) {
  return fmaf(-2.0f, __builtin_amdgcn_rcpf(exp2_fast(a) + 1.0f), 1.0f);
}

__device__ __forceinline__ unsigned short f2bf_rne(float f) {
  unsigned u = __float_as_uint(f);
  u = u + 0x7fffu + ((u >> 16) & 1u);
  return (unsigned short)(u >> 16);
}

// pack two floats to bf16 pair (round-half-up): {lo16: bf(a), hi16: bf(b)}
__device__ __forceinline__ unsigned pack_bf16(float a, float b) {
  unsigned ua = __float_as_uint(a) + 0x8000u;
  unsigned ub = __float_as_uint(b) + 0x8000u;
  return __builtin_amdgcn_perm(ub, ua, 0x07060302u);
}

// ---------------- fused prep kernel (unchanged from R6) ----------------
#define PK2_BLKS 512
#define MISC_BLKS 177
#define MISC_N 45184
#define SCAT_BLKS 512
#define PREP_GRID (PK2_BLKS + MISC_BLKS + SCAT_BLKS)

__global__ __launch_bounds__(256) void k_prep(
    const int* __restrict__ times,
    const float* __restrict__ W1, const float* __restrict__ b1,
    const float* __restrict__ W2, const float* __restrict__ b2,
    const float* __restrict__ W3, const float* __restrict__ b3,
    const float* __restrict__ W4, const float* __restrict__ b4,
    int* __restrict__ hdr, int* __restrict__ sortedIdx,
    unsigned short* __restrict__ packed23,
    float* __restrict__ w1p, float* __restrict__ b2p,
    float* __restrict__ b3p, float* __restrict__ b4p,
    unsigned short* __restrict__ W4p) {
  __shared__ int lh[NCLS], lbase[NCLS];

  int b = blockIdx.x;
  int tid = threadIdx.x;

  if (b < PK2_BLKS) {
    int cl = b >> 5;               // 0..15
    int k8 = b & 31;
    int j = tid;
    int l = cl >> 3, c = cl & 7;
    const float* W = (l ? W3 : W2) + c * 65536 + k8 * 8 * 256 + j;
    float v0 = W[0],        v1 = W[256],     v2 = W[2 * 256], v3 = W[3 * 256];
    float v4 = W[4 * 256],  v5 = W[5 * 256], v6 = W[6 * 256], v7 = W[7 * 256];
    uint4 pk;
    pk.x = (unsigned)f2bf_rne(PS * v0) | ((unsigned)f2bf_rne(PS * v1) << 16);
    pk.y = (unsigned)f2bf_rne(PS * v2) | ((unsigned)f2bf_rne(PS * v3) << 16);
    pk.z = (unsigned)f2bf_rne(PS * v4) | ((unsigned)f2bf_rne(PS * v5) << 16);
    pk.w = (unsigned)f2bf_rne(PS * v6) | ((unsigned)f2bf_rne(PS * v7) << 16);
    *(uint4*)&packed23[cl * 65536 + (k8 * 256 + j) * 8] = pk;
  } else if (b < PK2_BLKS + MISC_BLKS) {
    int e2 = (b - PK2_BLKS) * 256 + tid;
    if (e2 < 8192) {          // w1p: [c][j][4] = PS*{w0,w1,w2,b}
      int c = e2 >> 10, rem = e2 & 1023;
      int j = rem >> 2, t = rem & 3;
      float v = (t < 3) ? W1[c * 768 + t * 256 + j] : b1[c * 256 + j];
      w1p[e2] = PS * v;
    } else if (e2 < 10240) {
      int i = e2 - 8192;
      b2p[i] = PS * b2[i];
    } else if (e2 < 12288) {
      int i = e2 - 10240;
      b3p[i] = PS * b3[i];
    } else if (e2 < 12416) {  // b4p: [c][16]
      int i = e2 - 12288;
      int c = i >> 4, r = i & 15;
      b4p[i] = (r < 3) ? PS * b4[c * 3 + r] : 0.0f;
    } else if (e2 < MISC_N) { // W4p: [c][k/8][j(16)][k%8]
      int i = e2 - 12416;
      int c = i >> 12, rem = i & 4095;
      int jj = rem & 7, j = (rem >> 3) & 15, k = ((rem >> 7) << 3) + jj;
      float v = (j < 3) ? PS * W4[c * 768 + k * 3 + j] : 0.0f;
      W4p[c * 4096 + rem] = f2bf_rne(v);
    }
  } else {
    int sb = b - (PK2_BLKS + MISC_BLKS);
    if (tid < NCLS) lh[tid] = 0;
    __syncthreads();
    int i = sb * 256 + tid;
    int t = times[i];
    int r = atomicAdd(&lh[t], 1);
    __syncthreads();
    if (tid < NCLS) lbase[tid] = lh[tid] ? atomicAdd(&hdr[tid], lh[tid]) : 0;
    __syncthreads();
    sortedIdx[t * CAP + lbase[t] + r] = i;
  }
}

// ---------------- main MLP kernel ----------------
// 512 thr = 8 waves; block owns TWO 64-point tiles (same class), pipelined
// one layer apart. Each barrier segment = one tile's full MFMA k-loop
// (A-frags loaded once, reused over 4 m-tiles) + the other tile's
// independent VALU epilogue/L1:
//   S0 stage |S1 L1(0) |S2 L1(1)+K2(0) |S3 E2(0)+K2(1) |S4 E2(1)+K3(0)
//   |S5 E3(0)+K3(1) |S6 E3(1)+L4(0) |S7 L4(1)
// Wave w owns j-strip [w*32,+32). Abuf (B-frags): [k/8][m][k%8], in-place.
__global__ __launch_bounds__(512, 4) void k_mlp(
    const float* __restrict__ pos,
    const int* __restrict__ hdr, const int* __restrict__ sortedIdx,
    const unsigned short* __restrict__ packed23,
    const float* __restrict__ w1p, const float* __restrict__ b2p,
    const float* __restrict__ b3p, const float* __restrict__ b4p,
    const unsigned short* __restrict__ W4p,
    float* __restrict__ out) {

  __shared__ __align__(16) unsigned short Abuf[2][32][64][8];  // 64 KB
  __shared__ __align__(16) float4 w1i[256];                    // 4 KB
  __shared__ __align__(16) float xpos[2][64][4];               // 2 KB
  __shared__ int sIdx[2][64];

  int b = blockIdx.x;
  int tid = threadIdx.x;

  // derive (class, pair-tile) from per-class counts (128 points per block)
  int c = -1, t0 = 0, cnt = 0;
  {
    int ts = 0;
#pragma unroll
    for (int cc = 0; cc < NCLS; cc++) {
      int cc_cnt = hdr[cc];
      int tiles = (cc_cnt + 127) >> 7;
      if (b >= ts && b < ts + tiles) { c = cc; t0 = b - ts; cnt = cc_cnt; }
      ts += tiles;
    }
  }
  if (c < 0) return;
  int base0 = c * CAP + t0 * 128;
  int mc0 = min(64, cnt - t0 * 128);          // >= 1 by construction
  int mc1 = cnt - t0 * 128 - 64;              // may be <= 0 (empty tile 1)
  int base1 = (mc1 > 0) ? base0 + 64 : base0; // safe fallback
  int mc1c = max(mc1, 1);                     // clamp for index math
  mc1 = min(mc1, 64);

  int lane = tid & 63, w = tid >> 6;
  int quad = lane >> 4, l16 = lane & 15;
  int jbase = w * 32;

  const bf16x8* Af2 = (const bf16x8*)(packed23 + ((size_t)c << 16));
  const bf16x8* Af3 = (const bf16x8*)(packed23 + ((size_t)(8 + c) << 16));
  const float* bias2 = b2p + c * 256;
  const float* bias3 = b3p + c * 256;

  // ---- S0: stage sIdx (both tiles), xpos (direct gather), w1 ----
  if (tid < 128) {
    int t = tid >> 6, i = tid & 63;
    int bs = t ? base1 : base0;
    int mcc = t ? mc1c : mc0;
    sIdx[t][i] = sortedIdx[bs + min(i, mcc - 1)];
  }
  if (tid < 256) w1i[tid] = ((const float4*)(w1p + (size_t)c * 1024))[tid];
  if (tid >= 128) {
    int e = tid - 128;              // 0..383 covers 128 pts x 3 comps
    int m = e / 3, comp = e - 3 * m;
    int t = m >> 6, mm = m & 63;
    int bs = t ? base1 : base0;
    int mcc = t ? mc1c : mc0;
    int idx = sortedIdx[bs + min(mm, mcc - 1)];
    xpos[t][mm][comp] = pos[idx * 3 + comp];
  }

  // ---- building blocks ----
  auto l1 = [&](int t) {            // layer 1 for tile t (pure VALU)
    int m = tid & 63, jq = tid >> 6;  // jq 0..7, 32 j per thread
    float x0 = xpos[t][m][0], x1 = xpos[t][m][1], x2 = xpos[t][m][2];
#pragma unroll
    for (int i8 = 0; i8 < 4; i8++) {
      int j8 = jq * 4 + i8;
      unsigned pk[4];
#pragma unroll
      for (int jp = 0; jp < 4; jp++) {
        float tt[2];
#pragma unroll
        for (int u = 0; u < 2; u++) {
          float4 wv = w1i[j8 * 8 + jp * 2 + u];
          float a = fmaf(x0, wv.x, fmaf(x1, wv.y, fmaf(x2, wv.z, wv.w)));
          tt[u] = tanh_p2(a);
        }
        pk[jp] = pack_bf16(tt[0], tt[1]);
      }
      *(uint4*)&Abuf[t][j8][m][0] = make_uint4(pk[0], pk[1], pk[2], pk[3]);
    }
  };

  auto kloop = [&](int t, const bf16x8* __restrict__ Af,
                   const float* __restrict__ biasp, f32x4 (&acc)[2][4]) {
#pragma unroll
    for (int jf = 0; jf < 2; jf++) {
      f32x4 bv = *(const f32x4*)&biasp[jbase + jf * 16 + quad * 4];
#pragma unroll
      for (int mt = 0; mt < 4; mt++) acc[jf][mt] = bv;
    }
#pragma unroll
    for (int kb = 0; kb < 8; kb++) {
      int kq = kb * 4 + quad;
      bf16x8 af[2], bfr[4];
#pragma unroll
      for (int jf = 0; jf < 2; jf++)
        af[jf] = Af[kq * 256 + jbase + jf * 16 + l16];
#pragma unroll
      for (int mt = 0; mt < 4; mt++)
        bfr[mt] = *(const bf16x8*)&Abuf[t][kq][mt * 16 + l16][0];
#pragma unroll
      for (int jf = 0; jf < 2; jf++)
#pragma unroll
        for (int mt = 0; mt < 4; mt++)
          acc[jf][mt] = __builtin_amdgcn_mfma_f32_16x16x32_bf16(af[jf], bfr[mt], acc[jf][mt], 0, 0, 0);
    }
  };

  auto epi = [&](int t, f32x4 (&acc)[2][4]) {  // tanh+pack+write (VALU+LDS)
#pragma unroll
    for (int jf = 0; jf < 2; jf++) {
      int jbq = jbase + jf * 16 + quad * 4;    // 4 consecutive j per lane
#pragma unroll
      for (int mt = 0; mt < 4; mt++) {
        int m = mt * 16 + l16;
        float t0_ = tanh_p2(acc[jf][mt][0]);
        float t1_ = tanh_p2(acc[jf][mt][1]);
        float t2_ = tanh_p2(acc[jf][mt][2]);
        float t3_ = tanh_p2(acc[jf][mt][3]);
        uint2 pk = make_uint2(pack_bf16(t0_, t1_), pack_bf16(t2_, t3_));
        *(uint2*)&Abuf[t][jbq >> 3][m][jbq & 7] = pk;
      }
    }
  };

  auto l4 = [&](int t, int mCount) {  // waves 0..3 only; includes store
    f32x4 acc = *(const f32x4*)&b4p[c * 16 + quad * 4];
#pragma unroll
    for (int kb = 0; kb < 8; kb++) {
      int kq = kb * 4 + quad;
      bf16x8 a4 = *(const bf16x8*)&W4p[((size_t)c * 512 + kq * 16 + l16) * 8];
      bf16x8 b4f = *(const bf16x8*)&Abuf[t][kq][w * 16 + l16][0];
      acc = __builtin_amdgcn_mfma_f32_16x16x32_bf16(a4, b4f, acc, 0, 0, 0);
    }
    int m = w * 16 + l16;
    if (quad == 0 && m < mCount) {
      int o = sIdx[t][m] * 3;
      out[o + 0] = tanh_p2(acc[0]);
      out[o + 1] = tanh_p2(acc[1]);
      out[o + 2] = tanh_p2(acc[2]);
    }
  };

  f32x4 acc0[2][4], acc1[2][4];

  __syncthreads();                 // S0 done
  l1(0);                           // S1
  __syncthreads();
  kloop(0, Af2, bias2, acc0);      // S2: MFMA(T0) + VALU L1(T1)
  l1(1);
  __syncthreads();
  kloop(1, Af2, bias2, acc1);      // S3: MFMA(T1) + VALU E2(T0)
  epi(0, acc0);
  __syncthreads();
  kloop(0, Af3, bias3, acc0);      // S4: MFMA(T0,L3) + VALU E2(T1)
  epi(1, acc1);
  __syncthreads();
  kloop(1, Af3, bias3, acc1);      // S5: MFMA(T1,L3) + VALU E3(T0)
  epi(0, acc0);
  __syncthreads();
  epi(1, acc1);                    // S6: VALU E3(T1) + MFMA L4(T0)
  if (w < 4) l4(0, mc0);
  __syncthreads();
  if (w < 4) l4(1, mc1);           // S7
}

extern "C" void kernel_launch(void* const* d_in, const int* in_sizes, int n_in,
                              void* d_out, int out_size, void* d_ws, size_t ws_size,
                              hipStream_t stream) {
  const float* pos = (const float*)d_in[0];
  const int* times = (const int*)d_in[1];
  const float* W1 = (const float*)d_in[2];
  const float* b1 = (const float*)d_in[3];
  const float* W2 = (const float*)d_in[4];
  const float* b2 = (const float*)d_in[5];
  const float* W3 = (const float*)d_in[6];
  const float* b3 = (const float*)d_in[7];
  const float* W4 = (const float*)d_in[8];
  const float* b4 = (const float*)d_in[9];

  char* ws = (char*)d_ws;
  int* hdr = (int*)ws;
  int* sortedIdx = (int*)(ws + 4096);                    // 1 MB
  float* w1p = (float*)(ws + 1052672);                   // 32 KB
  float* b2p = (float*)(ws + 1085440);                   // 8 KB
  float* b3p = (float*)(ws + 1093632);                   // 8 KB
  float* b4p = (float*)(ws + 1101824);                   // 512 B
  unsigned short* W4p = (unsigned short*)(ws + 1102336); // 64 KB
  unsigned short* packed23 = (unsigned short*)(ws + (2u << 20)); // 2 MB
  float* out = (float*)d_out;

  hipMemsetAsync(d_ws, 0, 64, stream);
  k_prep<<<PREP_GRID, 256, 0, stream>>>(times, W1, b1, W2, b2, W3, b3, W4, b4,
                                        hdr, sortedIdx, packed23,
                                        w1p, b2p, b3p, b4p, W4p);
  k_mlp<<<N_PTS / 128 + NCLS, 512, 0, stream>>>(
      pos, hdr, sortedIdx, packed23, w1p, b2p, b3p, b4p, W4p, out);
}